// Round 1
// 6736.970 us; speedup vs baseline: 1.4753x; 1.4753x over previous
//
#include <hip/hip_runtime.h>
#include <math.h>

// Persistent fp16-MFMA LSTM, round 4. T=512, B=64, IN=512, H=1024, K=1536.
// 256 blocks x 256 threads (1 block/CU). Changes vs round 3:
//  - single monotonic arrival counter (no tree, no resets, no return-value
//    stalls); pollers wait for cnt >= 256*(t+1); no trailing __syncthreads
//    (each wave self-gates on the counter).
//  - out-stores (now packed float4) and the NEXT step's x-part MFMAs are
//    issued between arrival and poll -> they hide under barrier propagation.
//  - h written as one 8B packed fp16 sc1 store per (b) (3 shuffles gather the
//    4 contiguous columns) instead of 4x 2B scalar stores.
//  - two-accumulator h-MFMA chain; fast sigmoid/tanh via v_exp/v_rcp.

namespace {

constexpr int T_STEPS = 512;
constexpr int B = 64;
constexpr int IN = 512;
constexpr int H = 1024;
constexpr int K = IN + H;    // 1536
constexpr int NBLK = 256;
constexpr int NXMF = IN / 32;  // 16 x-part MFMAs
constexpr int NHMF = H / 32;   // 32 h-part MFMAs
constexpr int WPITCH = K + 8;  // one-time staging pitch (halves)

// ws layout (bytes) — unchanged from round 3 so NEED_PRE is identical.
constexpr size_t HBUF_OFF = 0;                                  // 2*B*H fp16
constexpr size_t XBUF_OFF = HBUF_OFF + 2ull * B * H * 2;        // 2*B*IN fp16
constexpr size_t BAR_OFF = XBUF_OFF + 2ull * B * IN * 2;        // 1056 uints
constexpr size_t COMBX_OFF = BAR_OFF + 1056ull * 4;             // T*B*IN fp16
constexpr size_t NEED_PRE = COMBX_OFF + (size_t)T_STEPS * B * IN * 2;

typedef __attribute__((ext_vector_type(8))) _Float16 f16x8;
typedef __attribute__((ext_vector_type(4))) float f32x4;

__device__ __forceinline__ f16x8 load_sc1_16B(const _Float16* p) {
  union {
    unsigned long long u[2];
    f16x8 v;
  } cv;
  const unsigned long long* q = (const unsigned long long*)p;
  cv.u[0] = __hip_atomic_load(q, __ATOMIC_RELAXED, __HIP_MEMORY_SCOPE_AGENT);
  cv.u[1] =
      __hip_atomic_load(q + 1, __ATOMIC_RELAXED, __HIP_MEMORY_SCOPE_AGENT);
  return cv.v;
}

__device__ __forceinline__ void store_sc1_u64(_Float16* p,
                                              unsigned long long v) {
  __hip_atomic_store((unsigned long long*)p, v, __ATOMIC_RELAXED,
                     __HIP_MEMORY_SCOPE_AGENT);
}

__device__ __forceinline__ void store_sc1_u32(unsigned* p, unsigned v) {
  __hip_atomic_store(p, v, __ATOMIC_RELAXED, __HIP_MEMORY_SCOPE_AGENT);
}

// |err| ~1e-7 relative — far below the fp16 h quantization already present.
__device__ __forceinline__ float fast_sigmoid(float z) {
  return __builtin_amdgcn_rcpf(1.0f + __expf(-z));
}
__device__ __forceinline__ float fast_tanh(float z) {
  return 1.0f - 2.0f * __builtin_amdgcn_rcpf(1.0f + __expf(2.0f * z));
}

// Prefilled-mode prep: combx[t][b][k] = fp16(x), zero hbuf, zero barrier.
__global__ void prep_pre(const float* __restrict__ x,
                         _Float16* __restrict__ combx,
                         _Float16* __restrict__ hbuf,
                         unsigned* __restrict__ bar) {
  const size_t i = (size_t)blockIdx.x * 256 + threadIdx.x;
  if (i < (size_t)T_STEPS * B * IN) combx[i] = (_Float16)x[i];
  if (i < 2ull * B * H) hbuf[i] = (_Float16)0.f;
  if (i < 1056) bar[i] = 0u;
}

// Fallback prep: xbuf[0] = fp16(x[0]), zero hbuf, zero barrier.
__global__ void prep_fb(const float* __restrict__ x,
                        _Float16* __restrict__ xbuf,
                        _Float16* __restrict__ hbuf,
                        unsigned* __restrict__ bar) {
  const size_t i = (size_t)blockIdx.x * 256 + threadIdx.x;
  if (i < (size_t)B * IN) xbuf[i] = (_Float16)x[i];
  if (i < 2ull * B * H) hbuf[i] = (_Float16)0.f;
  if (i < 1056) bar[i] = 0u;
}

template <bool PRE>
__global__ __launch_bounds__(256, 1) void lstm_persist(
    const float* __restrict__ x, const float* __restrict__ Wf,
    const float* __restrict__ Wi, const float* __restrict__ Wg,
    const float* __restrict__ Wo, const float* __restrict__ bf,
    const float* __restrict__ bi_, const float* __restrict__ bg,
    const float* __restrict__ bo, float* __restrict__ out,
    _Float16* __restrict__ combx, _Float16* __restrict__ xbuf,
    _Float16* __restrict__ hbuf, unsigned* __restrict__ bar) {
  __shared__ _Float16 Wlds[16 * WPITCH];  // one-time staging only

  const int blk = blockIdx.x;
  const int tid = threadIdx.x;
  const int j0 = blk * 4;

  // ---- one-time: stage W slice (coalesced), then lift B-frags to regs ----
  {
    const float* wptr[4] = {Wf, Wi, Wg, Wo};
#pragma unroll
    for (int g = 0; g < 4; ++g) {
      const float* wsrc = wptr[g];
      for (int it = 0; it < K / 256; ++it) {
        const int k = it * 256 + tid;
        const float4 w = *(const float4*)(wsrc + (size_t)k * H + j0);
        Wlds[(g * 4 + 0) * WPITCH + k] = (_Float16)w.x;
        Wlds[(g * 4 + 1) * WPITCH + k] = (_Float16)w.y;
        Wlds[(g * 4 + 2) * WPITCH + k] = (_Float16)w.z;
        Wlds[(g * 4 + 3) * WPITCH + k] = (_Float16)w.w;
      }
    }
  }
  __syncthreads();

  const int lane = tid & 63;
  const int wv = tid >> 6;
  const int q = lane >> 4;
  const int n = lane & 15;
  const int m0 = wv * 16;
  const int gate = n >> 2;
  const int jj = n & 3;
  const int arow = m0 + n;

  f16x8 Bfrag[NXMF + NHMF];  // 48 frags = 192 regs, resident all steps
#pragma unroll
  for (int kk = 0; kk < NXMF + NHMF; ++kk) {
    Bfrag[kk] = *(const f16x8*)(&Wlds[n * WPITCH + kk * 32 + q * 8]);
  }

  const float* bptr[4] = {bf, bi_, bg, bo};
  const float bias_v = bptr[gate][j0 + jj];

  float c_reg[4] = {0.f, 0.f, 0.f, 0.f};

  unsigned* cnt = bar;  // single monotonic arrival counter (bar[0])

  // x-part GEMM for step t -> acc_x (bias + x contribution). Runs in the
  // barrier-wait window for t>0.
  f32x4 acc_x;
  auto xpart = [&](int t) {
    f32x4 a = {bias_v, bias_v, bias_v, bias_v};
    if constexpr (PRE) {
      const _Float16* ab =
          combx + (size_t)t * B * IN + (size_t)arow * IN + q * 8;
#pragma unroll
      for (int kk = 0; kk < NXMF; ++kk) {
        f16x8 af = *(const f16x8*)(ab + kk * 32);
        a = __builtin_amdgcn_mfma_f32_16x16x32_f16(af, Bfrag[kk], a, 0, 0, 0);
      }
    } else {
      const _Float16* ab =
          xbuf + (size_t)(t & 1) * B * IN + (size_t)arow * IN + q * 8;
#pragma unroll
      for (int kk = 0; kk < NXMF; ++kk) {
        f16x8 af = load_sc1_16B(ab + kk * 32);
        a = __builtin_amdgcn_mfma_f32_16x16x32_f16(af, Bfrag[kk], a, 0, 0, 0);
      }
    }
    acc_x = a;
  };

  xpart(0);

  for (int t = 0; t < T_STEPS; ++t) {
    const _Float16* hb = hbuf + (size_t)(t & 1) * B * H;
    _Float16* hb_next = hbuf + (size_t)((t + 1) & 1) * B * H;

    // ---- h part: agent-scope loads, two accumulator chains ----
    f32x4 acc = acc_x;
    f32x4 accb = {0.f, 0.f, 0.f, 0.f};
    {
      const _Float16* ab = hb + (size_t)arow * H + q * 8;
#pragma unroll
      for (int kk = 0; kk < NHMF; kk += 2) {
        f16x8 a0 = load_sc1_16B(ab + kk * 32);
        f16x8 a1 = load_sc1_16B(ab + (kk + 1) * 32);
        acc = __builtin_amdgcn_mfma_f32_16x16x32_f16(a0, Bfrag[NXMF + kk], acc,
                                                     0, 0, 0);
        accb = __builtin_amdgcn_mfma_f32_16x16x32_f16(
            a1, Bfrag[NXMF + kk + 1], accb, 0, 0, 0);
      }
    }
    acc = acc + accb;

    // ---- epilogue: nonlinearities (all lanes, uniform code) ----
    float v[4];
#pragma unroll
    for (int r = 0; r < 4; ++r) {
      const float z = acc[r];
      v[r] = (gate == 2) ? fast_tanh(z) : fast_sigmoid(z);
    }
    float vi[4], vg[4], vo[4];
#pragma unroll
    for (int r = 0; r < 4; ++r) {
      vi[r] = __shfl(v[r], (lane + 4) & 63, 64);
      vg[r] = __shfl(v[r], (lane + 8) & 63, 64);
      vo[r] = __shfl(v[r], (lane + 12) & 63, 64);
    }
    float hv[4];
#pragma unroll
    for (int r = 0; r < 4; ++r) {
      const float c = fmaf(v[r], c_reg[r], vi[r] * vg[r]);
      c_reg[r] = c;
      hv[r] = vo[r] * fast_tanh(c);
    }
    // gather the 4 contiguous columns (j0..j0+3) onto lane n==0
    float h1[4], h2[4], h3[4];
#pragma unroll
    for (int r = 0; r < 4; ++r) {
      h1[r] = __shfl(hv[r], (lane + 1) & 63, 64);
      h2[r] = __shfl(hv[r], (lane + 2) & 63, 64);
      h3[r] = __shfl(hv[r], (lane + 3) & 63, 64);
    }
    // packed 8B fp16 h-store (must precede arrival)
    if (n == 0) {
#pragma unroll
      for (int r = 0; r < 4; ++r) {
        const int b = m0 + q * 4 + r;
        union {
          _Float16 h[4];
          unsigned long long u;
        } pk;
        pk.h[0] = (_Float16)hv[r];
        pk.h[1] = (_Float16)h1[r];
        pk.h[2] = (_Float16)h2[r];
        pk.h[3] = (_Float16)h3[r];
        store_sc1_u64(hb_next + (size_t)b * H + j0, pk.u);
      }
    }

    // ---- fallback: stage x[t+1] into next buffer (sc1 stores) ----
    if (!PRE && t + 1 < T_STEPS && tid < 16) {
      _Float16* xn = xbuf + (size_t)((t + 1) & 1) * B * IN;
      const int row = blk >> 2;
      const int off = (blk & 3) * 128 + tid * 8;
      const float* xs = x + (size_t)(t + 1) * B * IN + (size_t)row * IN + off;
      const float4 x0 = *(const float4*)xs;
      const float4 x1 = *(const float4*)(xs + 4);
      float vals[8] = {x0.x, x0.y, x0.z, x0.w, x1.x, x1.y, x1.z, x1.w};
#pragma unroll
      for (int i = 0; i < 4; ++i) {
        union {
          _Float16 h[2];
          unsigned u;
        } pk;
        pk.h[0] = (_Float16)vals[2 * i];
        pk.h[1] = (_Float16)vals[2 * i + 1];
        store_sc1_u32((unsigned*)(xn + (size_t)row * IN + off + 2 * i), pk.u);
      }
    }

    if (t + 1 < T_STEPS) {
      // drain h-stores (compiler emits vmcnt(0) before s_barrier), arrive
      __syncthreads();
      if (tid == 0) {
        __hip_atomic_fetch_add(cnt, 1u, __ATOMIC_RELAXED,
                               __HIP_MEMORY_SCOPE_AGENT);  // result unused
      }
      // out-stores + next-step x GEMM hide under barrier propagation
      if (n == 0) {
#pragma unroll
        for (int r = 0; r < 4; ++r) {
          const int b = m0 + q * 4 + r;
          const float4 o4 = make_float4(hv[r], h1[r], h2[r], h3[r]);
          *(float4*)(out + (size_t)t * B * H + (size_t)b * H + j0) = o4;
        }
      }
      if (PRE) xpart(t + 1);
      const unsigned target = 256u * (unsigned)(t + 1);
      while (__hip_atomic_load(cnt, __ATOMIC_RELAXED,
                               __HIP_MEMORY_SCOPE_AGENT) < target) {
        __builtin_amdgcn_s_sleep(1);
      }
      if (!PRE) xpart(t + 1);  // xbuf[t+1] only guaranteed visible after poll
    } else {
      // final step: out row + hx + cx (no barrier needed)
      float c1[4], c2[4], c3[4];
#pragma unroll
      for (int r = 0; r < 4; ++r) {
        c1[r] = __shfl(c_reg[r], (lane + 1) & 63, 64);
        c2[r] = __shfl(c_reg[r], (lane + 2) & 63, 64);
        c3[r] = __shfl(c_reg[r], (lane + 3) & 63, 64);
      }
      if (n == 0) {
#pragma unroll
        for (int r = 0; r < 4; ++r) {
          const int b = m0 + q * 4 + r;
          const float4 o4 = make_float4(hv[r], h1[r], h2[r], h3[r]);
          *(float4*)(out + (size_t)t * B * H + (size_t)b * H + j0) = o4;
          *(float4*)(out + (size_t)T_STEPS * B * H + (size_t)b * H + j0) =
              o4;  // hx
          const float4 c4 = make_float4(c_reg[r], c1[r], c2[r], c3[r]);
          *(float4*)(out + (size_t)T_STEPS * B * H + (size_t)B * H +
                     (size_t)b * H + j0) = c4;  // cx
        }
      }
    }
  }
}

}  // namespace

extern "C" void kernel_launch(void* const* d_in, const int* in_sizes, int n_in,
                              void* d_out, int out_size, void* d_ws,
                              size_t ws_size, hipStream_t stream) {
  const float* x = (const float*)d_in[0];
  const float* Wf = (const float*)d_in[1];
  const float* bf = (const float*)d_in[2];
  const float* Wi = (const float*)d_in[3];
  const float* bi = (const float*)d_in[4];
  const float* Wg = (const float*)d_in[5];
  const float* bg = (const float*)d_in[6];
  const float* Wo = (const float*)d_in[7];
  const float* bo = (const float*)d_in[8];
  float* out = (float*)d_out;

  char* ws = (char*)d_ws;
  _Float16* hbuf = (_Float16*)(ws + HBUF_OFF);
  _Float16* xbuf = (_Float16*)(ws + XBUF_OFF);
  unsigned* bar = (unsigned*)(ws + BAR_OFF);
  _Float16* combx = (_Float16*)(ws + COMBX_OFF);

  const bool pre = ws_size >= NEED_PRE;

  if (pre) {
    const size_t n = (size_t)T_STEPS * B * IN;
    prep_pre<<<(unsigned)((n + 255) / 256), 256, 0, stream>>>(x, combx, hbuf,
                                                              bar);
    lstm_persist<true><<<NBLK, 256, 0, stream>>>(
        x, Wf, Wi, Wg, Wo, bf, bi, bg, bo, out, combx, xbuf, hbuf, bar);
  } else {
    prep_fb<<<(2 * B * H + 255) / 256, 256, 0, stream>>>(x, xbuf, hbuf, bar);
    lstm_persist<false><<<NBLK, 256, 0, stream>>>(
        x, Wf, Wi, Wg, Wo, bf, bi, bg, bo, out, combx, xbuf, hbuf, bar);
  }
}

// Round 2
// 6010.520 us; speedup vs baseline: 1.6536x; 1.1209x over previous
//
#include <hip/hip_runtime.h>
#include <math.h>

// Persistent fp16-MFMA LSTM, round 5. T=512, B=64, IN=512, H=1024, K=1536.
// 256 blocks x 256 threads (1 block/CU). Changes vs round 4:
//  - barrier split: monotonic arrival counter + 8 replicated flag lines.
//    Last arriver (old==256(t+1)-1) publishes t+1 to the flags; pollers read
//    flags only (no poll/RMW contention on the counter line).
//  - wave 0 polls + acquire-fences; waves 1-3 wait at a raw s_barrier (no
//    vmcnt drain on the trailing barrier).
//  - h (and fallback x) consumed via PLAIN cached loads after a per-block
//    agent-scope acquire fence (buffer_inv): per-XCD L2 caches hbuf, cutting
//    ~32 MB/step of Infinity-Cache traffic to ~1 MB/step and IF latency to
//    L2 latency. Producers still write h via sc1 write-through stores drained
//    by the pre-arrival __syncthreads, so IF holds the truth before the flag.
//  - 4 parallel MFMA accumulator chains in the h-part, 2 in the x-part.

namespace {

constexpr int T_STEPS = 512;
constexpr int B = 64;
constexpr int IN = 512;
constexpr int H = 1024;
constexpr int K = IN + H;    // 1536
constexpr int NBLK = 256;
constexpr int NXMF = IN / 32;  // 16 x-part MFMAs
constexpr int NHMF = H / 32;   // 32 h-part MFMAs
constexpr int WPITCH = K + 8;  // one-time staging pitch (halves)

// ws layout (bytes) — unchanged from round 3/4 so NEED_PRE is identical.
constexpr size_t HBUF_OFF = 0;                                  // 2*B*H fp16
constexpr size_t XBUF_OFF = HBUF_OFF + 2ull * B * H * 2;        // 2*B*IN fp16
constexpr size_t BAR_OFF = XBUF_OFF + 2ull * B * IN * 2;        // 1056 uints
constexpr size_t COMBX_OFF = BAR_OFF + 1056ull * 4;             // T*B*IN fp16
constexpr size_t NEED_PRE = COMBX_OFF + (size_t)T_STEPS * B * IN * 2;

typedef __attribute__((ext_vector_type(8))) _Float16 f16x8;
typedef __attribute__((ext_vector_type(4))) float f32x4;

__device__ __forceinline__ void store_sc1_u64(_Float16* p,
                                              unsigned long long v) {
  __hip_atomic_store((unsigned long long*)p, v, __ATOMIC_RELAXED,
                     __HIP_MEMORY_SCOPE_AGENT);
}

__device__ __forceinline__ void store_sc1_u32(unsigned* p, unsigned v) {
  __hip_atomic_store(p, v, __ATOMIC_RELAXED, __HIP_MEMORY_SCOPE_AGENT);
}

// |err| ~1e-7 relative — far below the fp16 h quantization already present.
__device__ __forceinline__ float fast_sigmoid(float z) {
  return __builtin_amdgcn_rcpf(1.0f + __expf(-z));
}
__device__ __forceinline__ float fast_tanh(float z) {
  return 1.0f - 2.0f * __builtin_amdgcn_rcpf(1.0f + __expf(2.0f * z));
}

// Prefilled-mode prep: combx[t][b][k] = fp16(x), zero hbuf, zero barrier.
__global__ void prep_pre(const float* __restrict__ x,
                         _Float16* __restrict__ combx,
                         _Float16* __restrict__ hbuf,
                         unsigned* __restrict__ bar) {
  const size_t i = (size_t)blockIdx.x * 256 + threadIdx.x;
  if (i < (size_t)T_STEPS * B * IN) combx[i] = (_Float16)x[i];
  if (i < 2ull * B * H) hbuf[i] = (_Float16)0.f;
  if (i < 1056) bar[i] = 0u;
}

// Fallback prep: xbuf[0] = fp16(x[0]), zero hbuf, zero barrier.
__global__ void prep_fb(const float* __restrict__ x,
                        _Float16* __restrict__ xbuf,
                        _Float16* __restrict__ hbuf,
                        unsigned* __restrict__ bar) {
  const size_t i = (size_t)blockIdx.x * 256 + threadIdx.x;
  if (i < (size_t)B * IN) xbuf[i] = (_Float16)x[i];
  if (i < 2ull * B * H) hbuf[i] = (_Float16)0.f;
  if (i < 1056) bar[i] = 0u;
}

template <bool PRE>
__global__ __launch_bounds__(256, 1) void lstm_persist(
    const float* __restrict__ x, const float* __restrict__ Wf,
    const float* __restrict__ Wi, const float* __restrict__ Wg,
    const float* __restrict__ Wo, const float* __restrict__ bf,
    const float* __restrict__ bi_, const float* __restrict__ bg,
    const float* __restrict__ bo, float* __restrict__ out,
    _Float16* __restrict__ combx, _Float16* __restrict__ xbuf,
    _Float16* __restrict__ hbuf, unsigned* __restrict__ bar) {
  __shared__ _Float16 Wlds[16 * WPITCH];  // one-time staging only

  const int blk = blockIdx.x;
  const int tid = threadIdx.x;
  const int j0 = blk * 4;

  // ---- one-time: stage W slice (coalesced), then lift B-frags to regs ----
  {
    const float* wptr[4] = {Wf, Wi, Wg, Wo};
#pragma unroll
    for (int g = 0; g < 4; ++g) {
      const float* wsrc = wptr[g];
      for (int it = 0; it < K / 256; ++it) {
        const int k = it * 256 + tid;
        const float4 w = *(const float4*)(wsrc + (size_t)k * H + j0);
        Wlds[(g * 4 + 0) * WPITCH + k] = (_Float16)w.x;
        Wlds[(g * 4 + 1) * WPITCH + k] = (_Float16)w.y;
        Wlds[(g * 4 + 2) * WPITCH + k] = (_Float16)w.z;
        Wlds[(g * 4 + 3) * WPITCH + k] = (_Float16)w.w;
      }
    }
  }
  __syncthreads();

  const int lane = tid & 63;
  const int wv = tid >> 6;
  const int q = lane >> 4;
  const int n = lane & 15;
  const int m0 = wv * 16;
  const int gate = n >> 2;
  const int jj = n & 3;
  const int arow = m0 + n;

  f16x8 Bfrag[NXMF + NHMF];  // 48 frags = 192 regs, resident all steps
#pragma unroll
  for (int kk = 0; kk < NXMF + NHMF; ++kk) {
    Bfrag[kk] = *(const f16x8*)(&Wlds[n * WPITCH + kk * 32 + q * 8]);
  }

  const float* bptr[4] = {bf, bi_, bg, bo};
  const float bias_v = bptr[gate][j0 + jj];

  float c_reg[4] = {0.f, 0.f, 0.f, 0.f};

  unsigned* cnt = bar;                              // arrival counter
  unsigned* flagp = bar + 32 * ((blk & 7) + 1);     // this block's flag line

  // x-part GEMM for step t -> acc_x (bias + x contribution). Runs in the
  // barrier-wait window for t>0 (PRE) or just after the fence (fallback).
  f32x4 acc_x;
  auto xpart = [&](int t) {
    f32x4 a = {bias_v, bias_v, bias_v, bias_v};
    f32x4 b = {0.f, 0.f, 0.f, 0.f};
    const _Float16* ab =
        PRE ? (combx + (size_t)t * B * IN + (size_t)arow * IN + q * 8)
            : (xbuf + (size_t)(t & 1) * B * IN + (size_t)arow * IN + q * 8);
#pragma unroll
    for (int kk = 0; kk < NXMF; kk += 2) {
      f16x8 f0 = *(const f16x8*)(ab + kk * 32);
      f16x8 f1 = *(const f16x8*)(ab + (kk + 1) * 32);
      a = __builtin_amdgcn_mfma_f32_16x16x32_f16(f0, Bfrag[kk], a, 0, 0, 0);
      b = __builtin_amdgcn_mfma_f32_16x16x32_f16(f1, Bfrag[kk + 1], b, 0, 0,
                                                 0);
    }
    acc_x = a + b;
  };

  xpart(0);

  for (int t = 0; t < T_STEPS; ++t) {
    const _Float16* hb = hbuf + (size_t)(t & 1) * B * H;
    _Float16* hb_next = hbuf + (size_t)((t + 1) & 1) * B * H;

    // ---- h part: PLAIN cached loads (post-fence), 4 accumulator chains ----
    f32x4 a0 = acc_x;
    f32x4 a1 = {0.f, 0.f, 0.f, 0.f};
    f32x4 a2 = {0.f, 0.f, 0.f, 0.f};
    f32x4 a3 = {0.f, 0.f, 0.f, 0.f};
    {
      const _Float16* ab = hb + (size_t)arow * H + q * 8;
#pragma unroll
      for (int kk = 0; kk < NHMF; kk += 4) {
        f16x8 f0 = *(const f16x8*)(ab + kk * 32);
        f16x8 f1 = *(const f16x8*)(ab + (kk + 1) * 32);
        f16x8 f2 = *(const f16x8*)(ab + (kk + 2) * 32);
        f16x8 f3 = *(const f16x8*)(ab + (kk + 3) * 32);
        a0 = __builtin_amdgcn_mfma_f32_16x16x32_f16(f0, Bfrag[NXMF + kk], a0,
                                                    0, 0, 0);
        a1 = __builtin_amdgcn_mfma_f32_16x16x32_f16(f1, Bfrag[NXMF + kk + 1],
                                                    a1, 0, 0, 0);
        a2 = __builtin_amdgcn_mfma_f32_16x16x32_f16(f2, Bfrag[NXMF + kk + 2],
                                                    a2, 0, 0, 0);
        a3 = __builtin_amdgcn_mfma_f32_16x16x32_f16(f3, Bfrag[NXMF + kk + 3],
                                                    a3, 0, 0, 0);
      }
    }
    const f32x4 acc = (a0 + a1) + (a2 + a3);

    // ---- epilogue: nonlinearities (all lanes, uniform code) ----
    float v[4];
#pragma unroll
    for (int r = 0; r < 4; ++r) {
      const float z = acc[r];
      v[r] = (gate == 2) ? fast_tanh(z) : fast_sigmoid(z);
    }
    float vi[4], vg[4], vo[4];
#pragma unroll
    for (int r = 0; r < 4; ++r) {
      vi[r] = __shfl(v[r], (lane + 4) & 63, 64);
      vg[r] = __shfl(v[r], (lane + 8) & 63, 64);
      vo[r] = __shfl(v[r], (lane + 12) & 63, 64);
    }
    float hv[4];
#pragma unroll
    for (int r = 0; r < 4; ++r) {
      const float c = fmaf(v[r], c_reg[r], vi[r] * vg[r]);
      c_reg[r] = c;
      hv[r] = vo[r] * fast_tanh(c);
    }
    // gather the 4 contiguous columns (j0..j0+3) onto lane n==0
    float h1[4], h2[4], h3[4];
#pragma unroll
    for (int r = 0; r < 4; ++r) {
      h1[r] = __shfl(hv[r], (lane + 1) & 63, 64);
      h2[r] = __shfl(hv[r], (lane + 2) & 63, 64);
      h3[r] = __shfl(hv[r], (lane + 3) & 63, 64);
    }
    // packed 8B fp16 h-store, sc1 write-through (must precede arrival)
    if (n == 0) {
#pragma unroll
      for (int r = 0; r < 4; ++r) {
        const int b = m0 + q * 4 + r;
        union {
          _Float16 h[4];
          unsigned long long u;
        } pk;
        pk.h[0] = (_Float16)hv[r];
        pk.h[1] = (_Float16)h1[r];
        pk.h[2] = (_Float16)h2[r];
        pk.h[3] = (_Float16)h3[r];
        store_sc1_u64(hb_next + (size_t)b * H + j0, pk.u);
      }
    }

    // ---- fallback: stage x[t+1] into next buffer (sc1 stores) ----
    if (!PRE && t + 1 < T_STEPS && tid < 16) {
      _Float16* xn = xbuf + (size_t)((t + 1) & 1) * B * IN;
      const int row = blk >> 2;
      const int off = (blk & 3) * 128 + tid * 8;
      const float* xs = x + (size_t)(t + 1) * B * IN + (size_t)row * IN + off;
      const float4 x0 = *(const float4*)xs;
      const float4 x1 = *(const float4*)(xs + 4);
      float vals[8] = {x0.x, x0.y, x0.z, x0.w, x1.x, x1.y, x1.z, x1.w};
#pragma unroll
      for (int i = 0; i < 4; ++i) {
        union {
          _Float16 h[2];
          unsigned u;
        } pk;
        pk.h[0] = (_Float16)vals[2 * i];
        pk.h[1] = (_Float16)vals[2 * i + 1];
        store_sc1_u32((unsigned*)(xn + (size_t)row * IN + off + 2 * i), pk.u);
      }
    }

    if (t + 1 < T_STEPS) {
      // drain h-stores to the coherence point (compiler emits vmcnt(0)
      // before s_barrier), then arrive.
      __syncthreads();
      if (tid == 64) {  // wave-1 lane 0 arrives; wave 0 stays unstalled
        const unsigned a = __hip_atomic_fetch_add(cnt, 1u, __ATOMIC_RELAXED,
                                                  __HIP_MEMORY_SCOPE_AGENT);
        if (a == 256u * (unsigned)(t + 1) - 1u) {
#pragma unroll
          for (int i = 0; i < 8; ++i)
            store_sc1_u32(bar + 32 * (i + 1), (unsigned)(t + 1));
        }
      }
      // out-stores + next-step x GEMM hide under barrier propagation
      if (n == 0) {
#pragma unroll
        for (int r = 0; r < 4; ++r) {
          const int b = m0 + q * 4 + r;
          const float4 o4 = make_float4(hv[r], h1[r], h2[r], h3[r]);
          *(float4*)(out + (size_t)t * B * H + (size_t)b * H + j0) = o4;
        }
      }
      if (PRE) xpart(t + 1);
      // wave 0 polls the read-only flag line, then invalidates L1/L2 so the
      // whole block's plain h-loads refetch fresh data; waves 1-3 wait at a
      // raw barrier (no vmcnt drain).
      if (wv == 0) {
        while (__hip_atomic_load(flagp, __ATOMIC_RELAXED,
                                 __HIP_MEMORY_SCOPE_AGENT) <
               (unsigned)(t + 1)) {
          __builtin_amdgcn_s_sleep(1);
        }
        __builtin_amdgcn_fence(__ATOMIC_ACQUIRE, "agent");
      }
      asm volatile("" ::: "memory");
      __builtin_amdgcn_s_barrier();
      asm volatile("" ::: "memory");
      if (!PRE) xpart(t + 1);  // xbuf plain loads are safe only post-fence
    } else {
      // final step: out row + hx + cx (no barrier needed)
      float c1[4], c2[4], c3[4];
#pragma unroll
      for (int r = 0; r < 4; ++r) {
        c1[r] = __shfl(c_reg[r], (lane + 1) & 63, 64);
        c2[r] = __shfl(c_reg[r], (lane + 2) & 63, 64);
        c3[r] = __shfl(c_reg[r], (lane + 3) & 63, 64);
      }
      if (n == 0) {
#pragma unroll
        for (int r = 0; r < 4; ++r) {
          const int b = m0 + q * 4 + r;
          const float4 o4 = make_float4(hv[r], h1[r], h2[r], h3[r]);
          *(float4*)(out + (size_t)t * B * H + (size_t)b * H + j0) = o4;
          *(float4*)(out + (size_t)T_STEPS * B * H + (size_t)b * H + j0) =
              o4;  // hx
          const float4 c4 = make_float4(c_reg[r], c1[r], c2[r], c3[r]);
          *(float4*)(out + (size_t)T_STEPS * B * H + (size_t)B * H +
                     (size_t)b * H + j0) = c4;  // cx
        }
      }
    }
  }
}

}  // namespace

extern "C" void kernel_launch(void* const* d_in, const int* in_sizes, int n_in,
                              void* d_out, int out_size, void* d_ws,
                              size_t ws_size, hipStream_t stream) {
  const float* x = (const float*)d_in[0];
  const float* Wf = (const float*)d_in[1];
  const float* bf = (const float*)d_in[2];
  const float* Wi = (const float*)d_in[3];
  const float* bi = (const float*)d_in[4];
  const float* Wg = (const float*)d_in[5];
  const float* bg = (const float*)d_in[6];
  const float* Wo = (const float*)d_in[7];
  const float* bo = (const float*)d_in[8];
  float* out = (float*)d_out;

  char* ws = (char*)d_ws;
  _Float16* hbuf = (_Float16*)(ws + HBUF_OFF);
  _Float16* xbuf = (_Float16*)(ws + XBUF_OFF);
  unsigned* bar = (unsigned*)(ws + BAR_OFF);
  _Float16* combx = (_Float16*)(ws + COMBX_OFF);

  const bool pre = ws_size >= NEED_PRE;

  if (pre) {
    const size_t n = (size_t)T_STEPS * B * IN;
    prep_pre<<<(unsigned)((n + 255) / 256), 256, 0, stream>>>(x, combx, hbuf,
                                                              bar);
    lstm_persist<true><<<NBLK, 256, 0, stream>>>(
        x, Wf, Wi, Wg, Wo, bf, bi, bg, bo, out, combx, xbuf, hbuf, bar);
  } else {
    prep_fb<<<(2 * B * H + 255) / 256, 256, 0, stream>>>(x, xbuf, hbuf, bar);
    lstm_persist<false><<<NBLK, 256, 0, stream>>>(
        x, Wf, Wi, Wg, Wo, bf, bi, bg, bo, out, combx, xbuf, hbuf, bar);
  }
}